// Round 10
// baseline (999.705 us; speedup 1.0000x reference)
//
#include <hip/hip_runtime.h>
#include <math.h>

static inline int ceil_div(int a, int b) { return (a + b - 1) / b; }

// ---------------------------------------------------------------------------
// Setup kernels
// ---------------------------------------------------------------------------

__global__ __launch_bounds__(256) void setup_zero_pack(
    int* __restrict__ deg, int* __restrict__ fill, int n,
    const float* __restrict__ W1, const float* __restrict__ R1,
    const float* __restrict__ Wa, const float* __restrict__ Ra,
    const float* __restrict__ Wb, const float* __restrict__ Rb,
    const float* __restrict__ W2, const float* __restrict__ R2,
    float* __restrict__ Bc1, float* __restrict__ Bca,
    float* __restrict__ Bcb, float* __restrict__ Bc2) {
    int gid = blockIdx.x * 256 + threadIdx.x;
    int gstride = gridDim.x * 256;
    for (int i = gid; i < n; i += gstride) { deg[i] = 0; fill[i] = 0; }
    const int S1 = 256 * 192, S2 = 192 * 64, S4 = 64 * 48;
    const int TOT = S1 + 2 * S2 + S4;
    for (int i0 = gid; i0 < TOT; i0 += gstride) {
        int idx = i0;
        if (idx < S1) {
            int k = idx / 192, c = idx % 192;
            float v;
            if (c < 64)       v = W1[k * 64 + c];
            else if (c < 128) v = W1[256 * 64 + k * 64 + (c - 64)];
            else              v = R1[k * 64 + (c - 128)];
            Bc1[idx] = v;
            continue;
        }
        idx -= S1;
        if (idx < S2) { Bca[idx] = (idx < 8192) ? Wa[idx] : Ra[idx - 8192]; continue; }
        idx -= S2;
        if (idx < S2) { Bcb[idx] = (idx < 8192) ? Wb[idx] : Rb[idx - 8192]; continue; }
        idx -= S2;
        int k = idx / 48, c = idx % 48;
        float v;
        if (c < 16)      v = W2[k * 16 + c];
        else if (c < 32) v = W2[64 * 16 + k * 16 + (c - 16)];
        else             v = R2[k * 16 + (c - 32)];
        Bc2[idx] = v;
    }
}

__global__ __launch_bounds__(256) void hist_kernel(const int* __restrict__ dst,
                                                   int* __restrict__ deg, int E) {
    int e = blockIdx.x * 256 + threadIdx.x;
    if (e < E) atomicAdd(&deg[dst[e]], 1);
}

__global__ __launch_bounds__(256) void scan_blocksum(const int* __restrict__ deg,
                                                     int* __restrict__ bsum, int n) {
    __shared__ int red[256];
    int t = threadIdx.x;
    int base = blockIdx.x * 2048 + t * 8;
    int s = 0;
    #pragma unroll
    for (int i = 0; i < 8; ++i) {
        int idx = base + i;
        if (idx < n) s += deg[idx];
    }
    red[t] = s;
    __syncthreads();
    #pragma unroll
    for (int off = 128; off >= 1; off >>= 1) {
        if (t < off) red[t] += red[t + off];
        __syncthreads();
    }
    if (t == 0) bsum[blockIdx.x] = red[0];
}

__global__ __launch_bounds__(256) void scan_tops(int* __restrict__ bsum, int nb) {
    __shared__ int sh[256];
    int t = threadIdx.x;
    int orig = (t < nb) ? bsum[t] : 0;
    sh[t] = orig;
    __syncthreads();
    for (int off = 1; off < 256; off <<= 1) {
        int add = (t >= off) ? sh[t - off] : 0;
        __syncthreads();
        sh[t] += add;
        __syncthreads();
    }
    if (t < nb) bsum[t] = sh[t] - orig;  // exclusive prefix
}

__global__ __launch_bounds__(256) void scan_final(const int* __restrict__ deg,
                                                  const int* __restrict__ bsum,
                                                  int* __restrict__ rowp,
                                                  float* __restrict__ invd,
                                                  int n, int E) {
    __shared__ int sh[256];
    int t = threadIdx.x;
    int base = blockIdx.x * 2048 + t * 8;
    int loc[8];
    int s = 0;
    #pragma unroll
    for (int i = 0; i < 8; ++i) {
        int idx = base + i;
        int d = (idx < n) ? deg[idx] : 0;
        loc[i] = d;
        s += d;
    }
    sh[t] = s;
    __syncthreads();
    for (int off = 1; off < 256; off <<= 1) {
        int add = (t >= off) ? sh[t - off] : 0;
        __syncthreads();
        sh[t] += add;
        __syncthreads();
    }
    int run = bsum[blockIdx.x] + (sh[t] - s);
    #pragma unroll
    for (int i = 0; i < 8; ++i) {
        int idx = base + i;
        if (idx < n) {
            rowp[idx] = run;
            int d = loc[i];
            run += d;
            invd[idx] = 1.0f / (float)(d > 1 ? d : 1);
        }
    }
    if (blockIdx.x == 0 && t == 0) rowp[n] = E;
}

__global__ __launch_bounds__(256) void scatter_idx(const int* __restrict__ dst,
                                                   const int* __restrict__ rowp,
                                                   int* __restrict__ fill,
                                                   int* __restrict__ ei, int E) {
    int e = blockIdx.x * 256 + threadIdx.x;
    if (e >= E) return;
    int d = dst[e];
    int pos = rowp[d] + atomicAdd(&fill[d], 1);
    ei[pos] = e;
}

// Deterministic intra-node edge order. RK4 @ T=3 amplifies fp32 sum-order
// noise to O(1): determinism & order = correctness. NEVER change accumulation
// grouping downstream.
__global__ __launch_bounds__(256) void sort_fill(const int* __restrict__ rowp,
                                                 int* __restrict__ ei,
                                                 const int* __restrict__ src,
                                                 const float* __restrict__ p,
                                                 int* __restrict__ es,
                                                 float* __restrict__ ep, int n) {
    int node = blockIdx.x * 256 + threadIdx.x;
    if (node >= n) return;
    int b = rowp[node], e = rowp[node + 1];
    for (int i = b + 1; i < e; ++i) {
        int key = ei[i];
        int j = i - 1;
        while (j >= b && ei[j] > key) { ei[j + 1] = ei[j]; --j; }
        ei[j + 1] = key;
    }
    for (int i = b; i < e; ++i) {
        int id = ei[i];
        es[i] = src[id];
        ep[i] = p[id];
    }
}

// ---------------------------------------------------------------------------
// Edge aggregation (hidden convs): 16 lanes/node x float4.
// ---------------------------------------------------------------------------
__global__ __launch_bounds__(256) void edge_agg64_v4(const float* __restrict__ x,
                                                     const int* __restrict__ rowp,
                                                     const int* __restrict__ es,
                                                     const float* __restrict__ ep,
                                                     const float* __restrict__ invd,
                                                     float* __restrict__ agg, int n) {
    int gid = blockIdx.x * 256 + threadIdx.x;
    int node = gid >> 4;
    if (node >= n) return;
    int c4 = (gid & 15) << 2;
    int e = rowp[node], eend = rowp[node + 1];
    float sx = 0.f, sy = 0.f, sz = 0.f, sw = 0.f;
    float px = 0.f, py = 0.f, pz = 0.f, pw = 0.f;
    for (; e + 4 <= eend; e += 4) {
        int s0 = es[e], s1 = es[e + 1], s2 = es[e + 2], s3 = es[e + 3];
        float p0 = ep[e], p1 = ep[e + 1], p2 = ep[e + 2], p3 = ep[e + 3];
        float4 v0 = *reinterpret_cast<const float4*>(&x[(size_t)s0 * 64 + c4]);
        float4 v1 = *reinterpret_cast<const float4*>(&x[(size_t)s1 * 64 + c4]);
        float4 v2 = *reinterpret_cast<const float4*>(&x[(size_t)s2 * 64 + c4]);
        float4 v3 = *reinterpret_cast<const float4*>(&x[(size_t)s3 * 64 + c4]);
        sx += (v0.x + v1.x) + (v2.x + v3.x);
        sy += (v0.y + v1.y) + (v2.y + v3.y);
        sz += (v0.z + v1.z) + (v2.z + v3.z);
        sw += (v0.w + v1.w) + (v2.w + v3.w);
        px = fmaf(p0, v0.x, fmaf(p1, v1.x, fmaf(p2, v2.x, fmaf(p3, v3.x, px))));
        py = fmaf(p0, v0.y, fmaf(p1, v1.y, fmaf(p2, v2.y, fmaf(p3, v3.y, py))));
        pz = fmaf(p0, v0.z, fmaf(p1, v1.z, fmaf(p2, v2.z, fmaf(p3, v3.z, pz))));
        pw = fmaf(p0, v0.w, fmaf(p1, v1.w, fmaf(p2, v2.w, fmaf(p3, v3.w, pw))));
    }
    for (; e < eend; ++e) {
        int s = es[e];
        float pe = ep[e];
        float4 v = *reinterpret_cast<const float4*>(&x[(size_t)s * 64 + c4]);
        sx += v.x; sy += v.y; sz += v.z; sw += v.w;
        px = fmaf(pe, v.x, px); py = fmaf(pe, v.y, py);
        pz = fmaf(pe, v.z, pz); pw = fmaf(pe, v.w, pw);
    }
    float w = invd[node];
    float4 a0 = make_float4((sx - px) * w, (sy - py) * w, (sz - pz) * w, (sw - pw) * w);
    float4 a1 = make_float4(px * w, py * w, pz * w, pw * w);
    *reinterpret_cast<float4*>(&agg[(size_t)node * 128 + c4]) = a0;
    *reinterpret_cast<float4*>(&agg[(size_t)node * 128 + 64 + c4]) = a1;
}

// ---------------------------------------------------------------------------
// Hidden GEMM, SCALAR-B: lane = row (64-row tile), wave owns 16 cols whose
// base is made wave-uniform via readfirstlane -> B reads compile to s_load
// into SGPRs (off both the LDS pipe and the per-lane VMEM path — r8/r9 showed
// both of those saturate). Per kk: 1 stride-1 ds_read_b32 (A) + 16 FMAs:
// LDS/VALU = 0.18 (was 3x oversubscribed). db-A staging kept from r5.
// Same k-order per output -> bitwise identical.
// ---------------------------------------------------------------------------
__global__ __launch_bounds__(256) void hidden_gemm_s(
    const float* __restrict__ agg, const float* __restrict__ in,
    const float* __restrict__ B, const float* __restrict__ bias,
    int n, int mode, float* __restrict__ u_out,
    const float* __restrict__ hbuf, const float* __restrict__ acc_in,
    float* __restrict__ acc_out, float* __restrict__ t_out,
    float c1, float c2, float c3) {
    __shared__ __align__(16) float As[2][16][66];
    const int t = threadIdx.x;
    const int row0 = blockIdx.x * 64;
    const int lane = t & 63;
    const int c0 = __builtin_amdgcn_readfirstlane(t >> 6) << 4;  // 0/16/32/48
    const int lrow = t >> 2, lk = (t & 3) << 2;

    float4 av = make_float4(0.f, 0.f, 0.f, 0.f);
    {
        int r = row0 + lrow;
        if (r < n) av = *reinterpret_cast<const float4*>(&agg[(size_t)r * 128 + lk]);
    }
    As[0][lk + 0][lrow] = av.x; As[0][lk + 1][lrow] = av.y;
    As[0][lk + 2][lrow] = av.z; As[0][lk + 3][lrow] = av.w;
    __syncthreads();

    float acc[16];
    #pragma unroll
    for (int j = 0; j < 16; ++j) acc[j] = 0.f;

    for (int kt = 0; kt < 12; ++kt) {
        const int cur = kt & 1;
        if (kt + 1 < 12) {
            int k0 = (kt + 1) << 4;
            int r = row0 + lrow;
            int kk = k0 + lk;
            av = make_float4(0.f, 0.f, 0.f, 0.f);
            if (r < n)
                av = (kk < 128)
                    ? *reinterpret_cast<const float4*>(&agg[(size_t)r * 128 + kk])
                    : *reinterpret_cast<const float4*>(&in[(size_t)r * 64 + (kk - 128)]);
        }
        const int k0c = kt << 4;
        #pragma unroll
        for (int kk = 0; kk < 16; ++kk) {
            float a = As[cur][kk][lane];
            const float* bp = &B[(size_t)(k0c + kk) * 64 + c0];   // wave-uniform -> s_load
            #pragma unroll
            for (int j = 0; j < 16; ++j)
                acc[j] = fmaf(a, bp[j], acc[j]);
        }
        if (kt + 1 < 12) {
            const int nx = cur ^ 1;
            As[nx][lk + 0][lrow] = av.x; As[nx][lk + 1][lrow] = av.y;
            As[nx][lk + 2][lrow] = av.z; As[nx][lk + 3][lrow] = av.w;
        }
        __syncthreads();
    }

    int r = row0 + lane;
    if (r >= n) return;
    #pragma unroll
    for (int j4 = 0; j4 < 4; ++j4) {
        int c = c0 + (j4 << 2);
        size_t idx = (size_t)r * 64 + c;
        float4 bia = *reinterpret_cast<const float4*>(&bias[c]);
        float4 v = make_float4(acc[j4 * 4 + 0] + bia.x, acc[j4 * 4 + 1] + bia.y,
                               acc[j4 * 4 + 2] + bia.z, acc[j4 * 4 + 3] + bia.w);
        if (mode == 0) {
            *reinterpret_cast<float4*>(&u_out[idx]) = v;
        } else {
            float4 ai = make_float4(0.f, 0.f, 0.f, 0.f);
            if (acc_in) ai = *reinterpret_cast<const float4*>(&acc_in[idx]);
            float4 an = make_float4(ai.x + c3 * v.x, ai.y + c3 * v.y,
                                    ai.z + c3 * v.z, ai.w + c3 * v.w);
            *reinterpret_cast<float4*>(&acc_out[idx]) = an;
            float4 hb = *reinterpret_cast<const float4*>(&hbuf[idx]);
            float4 to = make_float4(hb.x + c1 * v.x + c2 * an.x,
                                    hb.y + c1 * v.y + c2 * an.y,
                                    hb.z + c1 * v.z + c2 * an.z,
                                    hb.w + c1 * v.w + c2 * an.w);
            *reinterpret_cast<float4*>(&t_out[idx]) = to;
        }
    }
}

// ---------------------------------------------------------------------------
// conv1 GEMM, SCALAR-B: lane = row, wave owns 48 cols (192/4). Per kk:
// 1 ds_read_b32 + 48 FMAs. VALU floor ~31 us.
// ---------------------------------------------------------------------------
__global__ __launch_bounds__(256) void conv1_gemm_s(const float* __restrict__ x,
                                                    const float* __restrict__ B,
                                                    int n, float* __restrict__ yz,
                                                    float* __restrict__ base,
                                                    const float* __restrict__ b1) {
    __shared__ __align__(16) float As[16][66];
    const int t = threadIdx.x;
    const int row0 = blockIdx.x * 64;
    const int lane = t & 63;
    const int c0 = __builtin_amdgcn_readfirstlane(t >> 6) * 48;  // 0/48/96/144
    const int lrow = t >> 2, lk = (t & 3) << 2;
    float acc[48];
    #pragma unroll
    for (int j = 0; j < 48; ++j) acc[j] = 0.f;

    for (int kt = 0; kt < 16; ++kt) {
        int k0 = kt << 4;
        float4 av = make_float4(0.f, 0.f, 0.f, 0.f);
        int r = row0 + lrow;
        if (r < n) av = *reinterpret_cast<const float4*>(&x[(size_t)r * 256 + k0 + lk]);
        As[lk + 0][lrow] = av.x; As[lk + 1][lrow] = av.y;
        As[lk + 2][lrow] = av.z; As[lk + 3][lrow] = av.w;
        __syncthreads();
        #pragma unroll
        for (int kk = 0; kk < 16; ++kk) {
            float a = As[kk][lane];
            const float* bp = &B[(size_t)(k0 + kk) * 192 + c0];   // wave-uniform -> s_load
            #pragma unroll
            for (int cg = 0; cg < 3; ++cg)
                #pragma unroll
                for (int j = 0; j < 16; ++j)
                    acc[cg * 16 + j] = fmaf(a, bp[cg * 16 + j], acc[cg * 16 + j]);
        }
        __syncthreads();
    }

    int r = row0 + lane;
    if (r >= n) return;
    #pragma unroll
    for (int j4 = 0; j4 < 12; ++j4) {
        int c = c0 + (j4 << 2);
        float4 v = make_float4(acc[j4 * 4 + 0], acc[j4 * 4 + 1],
                               acc[j4 * 4 + 2], acc[j4 * 4 + 3]);
        if (c < 128) {
            *reinterpret_cast<float4*>(&yz[(size_t)r * 128 + c]) = v;
        } else {
            int cc = c - 128;
            float4 bia = *reinterpret_cast<const float4*>(&b1[cc]);
            v.x += bia.x; v.y += bia.y; v.z += bia.z; v.w += bia.w;
            *reinterpret_cast<float4*>(&base[(size_t)r * 64 + cc]) = v;
        }
    }
}

// ---------------------------------------------------------------------------
// conv2 GEMM, SCALAR-B: K=64, M=48; wave owns 12 cols.
// ---------------------------------------------------------------------------
__global__ __launch_bounds__(256) void conv2_gemm_s(const float* __restrict__ A,
                                                    const float* __restrict__ B,
                                                    int n,
                                                    float* __restrict__ yz2,
                                                    float* __restrict__ base2,
                                                    const float* __restrict__ b2) {
    __shared__ __align__(16) float As[16][66];
    const int t = threadIdx.x;
    const int row0 = blockIdx.x * 64;
    const int lane = t & 63;
    const int c0 = __builtin_amdgcn_readfirstlane(t >> 6) * 12;  // 0/12/24/36
    const int lrow = t >> 2, lk = (t & 3) << 2;
    float acc[12];
    #pragma unroll
    for (int j = 0; j < 12; ++j) acc[j] = 0.f;

    for (int kt = 0; kt < 4; ++kt) {
        int k0 = kt << 4;
        float4 av = make_float4(0.f, 0.f, 0.f, 0.f);
        int r = row0 + lrow;
        if (r < n) av = *reinterpret_cast<const float4*>(&A[(size_t)r * 64 + k0 + lk]);
        As[lk + 0][lrow] = av.x; As[lk + 1][lrow] = av.y;
        As[lk + 2][lrow] = av.z; As[lk + 3][lrow] = av.w;
        __syncthreads();
        #pragma unroll
        for (int kk = 0; kk < 16; ++kk) {
            float a = As[kk][lane];
            const float* bp = &B[(size_t)(k0 + kk) * 48 + c0];
            #pragma unroll
            for (int j = 0; j < 12; ++j)
                acc[j] = fmaf(a, bp[j], acc[j]);
        }
        __syncthreads();
    }

    int r = row0 + lane;
    if (r >= n) return;
    #pragma unroll
    for (int j4 = 0; j4 < 3; ++j4) {
        int c = c0 + (j4 << 2);
        float4 v = make_float4(acc[j4 * 4 + 0], acc[j4 * 4 + 1],
                               acc[j4 * 4 + 2], acc[j4 * 4 + 3]);
        if (c < 32) {
            *reinterpret_cast<float4*>(&yz2[(size_t)r * 32 + c]) = v;
        } else {
            int cc = c - 32;
            float4 bia = *reinterpret_cast<const float4*>(&b2[cc]);
            v.x += bia.x; v.y += bia.y; v.z += bia.z; v.w += bia.w;
            *reinterpret_cast<float4*>(&base2[(size_t)r * 16 + cc]) = v;
        }
    }
}

// ---------------------------------------------------------------------------
// Edge transform kernels (unchanged)
// ---------------------------------------------------------------------------

__global__ __launch_bounds__(256) void edge_tf64_v8(const float* __restrict__ yz,
                                                    const int* __restrict__ rowp,
                                                    const int* __restrict__ es,
                                                    const float* __restrict__ ep,
                                                    const float* __restrict__ invd,
                                                    const float* __restrict__ base,
                                                    float* __restrict__ out, int n) {
    int gid = blockIdx.x * 256 + threadIdx.x;
    int node = gid >> 3;
    if (node >= n) return;
    int c8 = (gid & 7) << 3;
    int e = rowp[node], eend = rowp[node + 1];
    float a[8] = {0.f, 0.f, 0.f, 0.f, 0.f, 0.f, 0.f, 0.f};
    for (; e + 2 <= eend; e += 2) {
        int s0 = es[e], s1 = es[e + 1];
        float p0 = ep[e], p1 = ep[e + 1];
        float4 y0a = *reinterpret_cast<const float4*>(&yz[(size_t)s0 * 128 + c8]);
        float4 y0b = *reinterpret_cast<const float4*>(&yz[(size_t)s0 * 128 + c8 + 4]);
        float4 z0a = *reinterpret_cast<const float4*>(&yz[(size_t)s0 * 128 + 64 + c8]);
        float4 z0b = *reinterpret_cast<const float4*>(&yz[(size_t)s0 * 128 + 64 + c8 + 4]);
        float4 y1a = *reinterpret_cast<const float4*>(&yz[(size_t)s1 * 128 + c8]);
        float4 y1b = *reinterpret_cast<const float4*>(&yz[(size_t)s1 * 128 + c8 + 4]);
        float4 z1a = *reinterpret_cast<const float4*>(&yz[(size_t)s1 * 128 + 64 + c8]);
        float4 z1b = *reinterpret_cast<const float4*>(&yz[(size_t)s1 * 128 + 64 + c8 + 4]);
        const float* ya0 = &y0a.x; const float* yb0 = &y0b.x;
        const float* za0 = &z0a.x; const float* zb0 = &z0b.x;
        const float* ya1 = &y1a.x; const float* yb1 = &y1b.x;
        const float* za1 = &z1a.x; const float* zb1 = &z1b.x;
        #pragma unroll
        for (int j = 0; j < 4; ++j) {
            a[j]     += fmaf(p0, za0[j] - ya0[j], ya0[j]) + fmaf(p1, za1[j] - ya1[j], ya1[j]);
            a[4 + j] += fmaf(p0, zb0[j] - yb0[j], yb0[j]) + fmaf(p1, zb1[j] - yb1[j], yb1[j]);
        }
    }
    for (; e < eend; ++e) {
        int s = es[e];
        float pe = ep[e];
        float4 ya = *reinterpret_cast<const float4*>(&yz[(size_t)s * 128 + c8]);
        float4 yb = *reinterpret_cast<const float4*>(&yz[(size_t)s * 128 + c8 + 4]);
        float4 za = *reinterpret_cast<const float4*>(&yz[(size_t)s * 128 + 64 + c8]);
        float4 zb = *reinterpret_cast<const float4*>(&yz[(size_t)s * 128 + 64 + c8 + 4]);
        const float* fy = &ya.x; const float* gy = &yb.x;
        const float* fz = &za.x; const float* gz = &zb.x;
        #pragma unroll
        for (int j = 0; j < 4; ++j) {
            a[j]     += fmaf(pe, fz[j] - fy[j], fy[j]);
            a[4 + j] += fmaf(pe, gz[j] - gy[j], gy[j]);
        }
    }
    float w = invd[node];
    size_t idx = (size_t)node * 64 + c8;
    float4 ba = *reinterpret_cast<const float4*>(&base[idx]);
    float4 bbv = *reinterpret_cast<const float4*>(&base[idx + 4]);
    float4 o0 = make_float4(tanhf(fmaf(a[0], w, ba.x)), tanhf(fmaf(a[1], w, ba.y)),
                            tanhf(fmaf(a[2], w, ba.z)), tanhf(fmaf(a[3], w, ba.w)));
    float4 o1 = make_float4(tanhf(fmaf(a[4], w, bbv.x)), tanhf(fmaf(a[5], w, bbv.y)),
                            tanhf(fmaf(a[6], w, bbv.z)), tanhf(fmaf(a[7], w, bbv.w)));
    *reinterpret_cast<float4*>(&out[idx]) = o0;
    *reinterpret_cast<float4*>(&out[idx + 4]) = o1;
}

__global__ __launch_bounds__(256) void edge_tf16_lsm(const float* __restrict__ yz,
                                                     const int* __restrict__ rowp,
                                                     const int* __restrict__ es,
                                                     const float* __restrict__ ep,
                                                     const float* __restrict__ invd,
                                                     const float* __restrict__ base,
                                                     float* __restrict__ out, int n) {
    int gid = blockIdx.x * 256 + threadIdx.x;
    int node = gid >> 4;
    if (node >= n) return;
    int c = gid & 15;
    int e = rowp[node], eend = rowp[node + 1];
    float a = 0.f;
    for (; e + 4 <= eend; e += 4) {
        int s0 = es[e], s1 = es[e + 1], s2 = es[e + 2], s3 = es[e + 3];
        float p0 = ep[e], p1 = ep[e + 1], p2 = ep[e + 2], p3 = ep[e + 3];
        float y0 = yz[(size_t)s0 * 32 + c],      z0 = yz[(size_t)s0 * 32 + 16 + c];
        float y1 = yz[(size_t)s1 * 32 + c],      z1 = yz[(size_t)s1 * 32 + 16 + c];
        float y2 = yz[(size_t)s2 * 32 + c],      z2 = yz[(size_t)s2 * 32 + 16 + c];
        float y3 = yz[(size_t)s3 * 32 + c],      z3 = yz[(size_t)s3 * 32 + 16 + c];
        a += fmaf(p0, z0 - y0, y0);
        a += fmaf(p1, z1 - y1, y1);
        a += fmaf(p2, z2 - y2, y2);
        a += fmaf(p3, z3 - y3, y3);
    }
    for (; e < eend; ++e) {
        int s = es[e]; float pe = ep[e];
        float y = yz[(size_t)s * 32 + c], z = yz[(size_t)s * 32 + 16 + c];
        a += fmaf(pe, z - y, y);
    }
    float o = tanhf(a * invd[node] + base[(size_t)node * 16 + c]);
    float m = o;
    #pragma unroll
    for (int off = 8; off >= 1; off >>= 1) m = fmaxf(m, __shfl_xor(m, off, 16));
    float ex = expf(o - m);
    float s = ex;
    #pragma unroll
    for (int off = 8; off >= 1; off >>= 1) s += __shfl_xor(s, off, 16);
    out[(size_t)node * 16 + c] = (o - m) - logf(s);
}

// ---------------------------------------------------------------------------
// Host-side launcher
// ---------------------------------------------------------------------------

static void hidden_conv(hipStream_t stream, const float* in, float* agg,
                        const int* rowp, const int* es, const float* ep,
                        const float* invd, const float* Bc, const float* bias, int n,
                        int mode, float* u_out,
                        const float* h, const float* acc_in, float* acc_out,
                        float* t_out, float c1, float c2, float c3) {
    edge_agg64_v4<<<ceil_div(n * 16, 256), 256, 0, stream>>>(in, rowp, es, ep, invd,
                                                             agg, n);
    hidden_gemm_s<<<ceil_div(n, 64), 256, 0, stream>>>(agg, in, Bc, bias, n, mode,
                                                       u_out, h, acc_in, acc_out,
                                                       t_out, c1, c2, c3);
}

extern "C" void kernel_launch(void* const* d_in, const int* in_sizes, int n_in,
                              void* d_out, int out_size, void* d_ws, size_t ws_size,
                              hipStream_t stream) {
    const float* x  = (const float*)d_in[0];
    const float* pE = (const float*)d_in[1];
    const int*   sr = (const int*)d_in[2];
    const int*   ds = (const int*)d_in[3];
    const float* W1 = (const float*)d_in[4];
    const float* R1 = (const float*)d_in[5];
    const float* b1 = (const float*)d_in[6];
    const float* Wa = (const float*)d_in[7];
    const float* Ra = (const float*)d_in[8];
    const float* ba = (const float*)d_in[9];
    const float* Wb = (const float*)d_in[10];
    const float* Rb = (const float*)d_in[11];
    const float* bb = (const float*)d_in[12];
    const float* W2 = (const float*)d_in[13];
    const float* R2 = (const float*)d_in[14];
    const float* b2 = (const float*)d_in[15];
    const int n = in_sizes[0] / 256;
    const int E = in_sizes[2];
    float* out = (float*)d_out;

    char* w = (char*)d_ws;
    auto alloc = [&](size_t bytes) -> void* {
        void* ptr = (void*)w;
        w += (bytes + 255) & ~(size_t)255;
        return ptr;
    };
    int nscan = ceil_div(n, 2048);
    int*   deg  = (int*)alloc((size_t)n * 4);
    int*   fill = (int*)alloc((size_t)n * 4);
    int*   rowp = (int*)alloc((size_t)(n + 1) * 4);
    float* invd = (float*)alloc((size_t)n * 4);
    int*   bsum = (int*)alloc((size_t)256 * 4);
    int*   ei   = (int*)alloc((size_t)E * 4);
    int*   es   = (int*)alloc((size_t)E * 4);
    float* ep   = (float*)alloc((size_t)E * 4);
    float* Bc1  = (float*)alloc((size_t)256 * 192 * 4);
    float* Bca  = (float*)alloc((size_t)192 * 64 * 4);
    float* Bcb  = (float*)alloc((size_t)192 * 64 * 4);
    float* Bc2  = (float*)alloc((size_t)64 * 48 * 4);
    float* big0 = (float*)alloc((size_t)n * 128 * 4);  // yz / agg buffer
    float* big1 = (float*)alloc((size_t)n * 64 * 4);   // base buffer
    float* h    = (float*)alloc((size_t)n * 64 * 4);
    float* u    = (float*)alloc((size_t)n * 64 * 4);
    float* tb   = (float*)alloc((size_t)n * 64 * 4);
    float* acc  = (float*)alloc((size_t)n * 64 * 4);

    setup_zero_pack<<<288, 256, 0, stream>>>(deg, fill, n, W1, R1, Wa, Ra, Wb, Rb,
                                             W2, R2, Bc1, Bca, Bcb, Bc2);
    hist_kernel<<<ceil_div(E, 256), 256, 0, stream>>>(ds, deg, E);
    scan_blocksum<<<nscan, 256, 0, stream>>>(deg, bsum, n);
    scan_tops<<<1, 256, 0, stream>>>(bsum, nscan);
    scan_final<<<nscan, 256, 0, stream>>>(deg, bsum, rowp, invd, n, E);
    scatter_idx<<<ceil_div(E, 256), 256, 0, stream>>>(ds, rowp, fill, ei, E);
    sort_fill<<<ceil_div(n, 256), 256, 0, stream>>>(rowp, ei, sr, pE, es, ep, n);

    // conv1: x @ [W1_0|W1_1|R1] -> yz(big0), base(big1)+b1; then edge transform
    conv1_gemm_s<<<ceil_div(n, 64), 256, 0, stream>>>(x, Bc1, n, big0, big1, b1);
    edge_tf64_v8<<<ceil_div(n * 8, 256), 256, 0, stream>>>(big0, rowp, es, ep, invd,
                                                           big1, h, n);

    // RK4 over f(y) = conv_b(conv_a(y)), T=3
    // k1
    hidden_conv(stream, h, big0, rowp, es, ep, invd, Bca, ba, n, 0, u,
                nullptr, nullptr, nullptr, nullptr, 0.f, 0.f, 0.f);
    hidden_conv(stream, u, big0, rowp, es, ep, invd, Bcb, bb, n, 1, nullptr,
                h, nullptr, acc, tb, 1.5f, 0.f, 1.f);
    // k2
    hidden_conv(stream, tb, big0, rowp, es, ep, invd, Bca, ba, n, 0, u,
                nullptr, nullptr, nullptr, nullptr, 0.f, 0.f, 0.f);
    hidden_conv(stream, u, big0, rowp, es, ep, invd, Bcb, bb, n, 1, nullptr,
                h, acc, acc, tb, 1.5f, 0.f, 2.f);
    // k3
    hidden_conv(stream, tb, big0, rowp, es, ep, invd, Bca, ba, n, 0, u,
                nullptr, nullptr, nullptr, nullptr, 0.f, 0.f, 0.f);
    hidden_conv(stream, u, big0, rowp, es, ep, invd, Bcb, bb, n, 1, nullptr,
                h, acc, acc, tb, 3.f, 0.f, 2.f);
    // k4: t_out becomes h_new = h + 0.5*(k1+2k2+2k3+k4)
    hidden_conv(stream, tb, big0, rowp, es, ep, invd, Bca, ba, n, 0, u,
                nullptr, nullptr, nullptr, nullptr, 0.f, 0.f, 0.f);
    hidden_conv(stream, u, big0, rowp, es, ep, invd, Bcb, bb, n, 1, nullptr,
                h, acc, acc, tb, 0.f, 0.5f, 1.f);

    // conv2: h_new @ [W2_0|W2_1|R2] -> yz2(big0,w=32), base2(big1,w=16)+b2
    conv2_gemm_s<<<ceil_div(n, 64), 256, 0, stream>>>(tb, Bc2, n, big0, big1, b2);
    edge_tf16_lsm<<<ceil_div(n * 16, 256), 256, 0, stream>>>(big0, rowp, es, ep, invd,
                                                             big1, out, n);
}

// Round 11
// 884.429 us; speedup vs baseline: 1.1303x; 1.1303x over previous
//
#include <hip/hip_runtime.h>
#include <math.h>

static inline int ceil_div(int a, int b) { return (a + b - 1) / b; }

// ---------------------------------------------------------------------------
// Setup kernels
// ---------------------------------------------------------------------------

__global__ __launch_bounds__(256) void setup_zero_pack(
    int* __restrict__ deg, int* __restrict__ fill, int n,
    const float* __restrict__ W1, const float* __restrict__ R1,
    const float* __restrict__ Wa, const float* __restrict__ Ra,
    const float* __restrict__ Wb, const float* __restrict__ Rb,
    const float* __restrict__ W2, const float* __restrict__ R2,
    float* __restrict__ Bc1, float* __restrict__ Bca,
    float* __restrict__ Bcb, float* __restrict__ Bc2) {
    int gid = blockIdx.x * 256 + threadIdx.x;
    int gstride = gridDim.x * 256;
    for (int i = gid; i < n; i += gstride) { deg[i] = 0; fill[i] = 0; }
    const int S1 = 256 * 192, S2 = 192 * 64, S4 = 64 * 48;
    const int TOT = S1 + 2 * S2 + S4;
    for (int i0 = gid; i0 < TOT; i0 += gstride) {
        int idx = i0;
        if (idx < S1) {
            int k = idx / 192, c = idx % 192;
            float v;
            if (c < 64)       v = W1[k * 64 + c];
            else if (c < 128) v = W1[256 * 64 + k * 64 + (c - 64)];
            else              v = R1[k * 64 + (c - 128)];
            Bc1[idx] = v;
            continue;
        }
        idx -= S1;
        if (idx < S2) { Bca[idx] = (idx < 8192) ? Wa[idx] : Ra[idx - 8192]; continue; }
        idx -= S2;
        if (idx < S2) { Bcb[idx] = (idx < 8192) ? Wb[idx] : Rb[idx - 8192]; continue; }
        idx -= S2;
        int k = idx / 48, c = idx % 48;
        float v;
        if (c < 16)      v = W2[k * 16 + c];
        else if (c < 32) v = W2[64 * 16 + k * 16 + (c - 16)];
        else             v = R2[k * 16 + (c - 32)];
        Bc2[idx] = v;
    }
}

__global__ __launch_bounds__(256) void hist_kernel(const int* __restrict__ dst,
                                                   int* __restrict__ deg, int E) {
    int e = blockIdx.x * 256 + threadIdx.x;
    if (e < E) atomicAdd(&deg[dst[e]], 1);
}

__global__ __launch_bounds__(256) void scan_blocksum(const int* __restrict__ deg,
                                                     int* __restrict__ bsum, int n) {
    __shared__ int red[256];
    int t = threadIdx.x;
    int base = blockIdx.x * 2048 + t * 8;
    int s = 0;
    #pragma unroll
    for (int i = 0; i < 8; ++i) {
        int idx = base + i;
        if (idx < n) s += deg[idx];
    }
    red[t] = s;
    __syncthreads();
    #pragma unroll
    for (int off = 128; off >= 1; off >>= 1) {
        if (t < off) red[t] += red[t + off];
        __syncthreads();
    }
    if (t == 0) bsum[blockIdx.x] = red[0];
}

__global__ __launch_bounds__(256) void scan_tops(int* __restrict__ bsum, int nb) {
    __shared__ int sh[256];
    int t = threadIdx.x;
    int orig = (t < nb) ? bsum[t] : 0;
    sh[t] = orig;
    __syncthreads();
    for (int off = 1; off < 256; off <<= 1) {
        int add = (t >= off) ? sh[t - off] : 0;
        __syncthreads();
        sh[t] += add;
        __syncthreads();
    }
    if (t < nb) bsum[t] = sh[t] - orig;  // exclusive prefix
}

__global__ __launch_bounds__(256) void scan_final(const int* __restrict__ deg,
                                                  const int* __restrict__ bsum,
                                                  int* __restrict__ rowp,
                                                  float* __restrict__ invd,
                                                  int n, int E) {
    __shared__ int sh[256];
    int t = threadIdx.x;
    int base = blockIdx.x * 2048 + t * 8;
    int loc[8];
    int s = 0;
    #pragma unroll
    for (int i = 0; i < 8; ++i) {
        int idx = base + i;
        int d = (idx < n) ? deg[idx] : 0;
        loc[i] = d;
        s += d;
    }
    sh[t] = s;
    __syncthreads();
    for (int off = 1; off < 256; off <<= 1) {
        int add = (t >= off) ? sh[t - off] : 0;
        __syncthreads();
        sh[t] += add;
        __syncthreads();
    }
    int run = bsum[blockIdx.x] + (sh[t] - s);
    #pragma unroll
    for (int i = 0; i < 8; ++i) {
        int idx = base + i;
        if (idx < n) {
            rowp[idx] = run;
            int d = loc[i];
            run += d;
            invd[idx] = 1.0f / (float)(d > 1 ? d : 1);
        }
    }
    if (blockIdx.x == 0 && t == 0) rowp[n] = E;
}

__global__ __launch_bounds__(256) void scatter_idx(const int* __restrict__ dst,
                                                   const int* __restrict__ rowp,
                                                   int* __restrict__ fill,
                                                   int* __restrict__ ei, int E) {
    int e = blockIdx.x * 256 + threadIdx.x;
    if (e >= E) return;
    int d = dst[e];
    int pos = rowp[d] + atomicAdd(&fill[d], 1);
    ei[pos] = e;
}

// Deterministic intra-node edge order. RK4 @ T=3 amplifies fp32 sum-order
// noise to O(1): determinism & order = correctness. NEVER change accumulation
// grouping downstream (load batching is fine; FMA sequence is not).
__global__ __launch_bounds__(256) void sort_fill(const int* __restrict__ rowp,
                                                 int* __restrict__ ei,
                                                 const int* __restrict__ src,
                                                 const float* __restrict__ p,
                                                 int* __restrict__ es,
                                                 float* __restrict__ ep, int n) {
    int node = blockIdx.x * 256 + threadIdx.x;
    if (node >= n) return;
    int b = rowp[node], e = rowp[node + 1];
    for (int i = b + 1; i < e; ++i) {
        int key = ei[i];
        int j = i - 1;
        while (j >= b && ei[j] > key) { ei[j + 1] = ei[j]; --j; }
        ei[j + 1] = key;
    }
    for (int i = b; i < e; ++i) {
        int id = ei[i];
        es[i] = src[id];
        ep[i] = p[id];
    }
}

// ---------------------------------------------------------------------------
// Edge aggregation, 8-edge LOAD batching (16 outstanding bytes-level loads per
// lane incl. es/ep) with the ORIGINAL 4-edge math grouping preserved ->
// bitwise identical, ~2x MLP for this latency-bound gather.
// ---------------------------------------------------------------------------
__global__ __launch_bounds__(256) void edge_agg64_u8(const float* __restrict__ x,
                                                     const int* __restrict__ rowp,
                                                     const int* __restrict__ es,
                                                     const float* __restrict__ ep,
                                                     const float* __restrict__ invd,
                                                     float* __restrict__ agg, int n) {
    int gid = blockIdx.x * 256 + threadIdx.x;
    int node = gid >> 4;
    if (node >= n) return;
    int c4 = (gid & 15) << 2;
    int e = rowp[node], eend = rowp[node + 1];
    float sx = 0.f, sy = 0.f, sz = 0.f, sw = 0.f;
    float px = 0.f, py = 0.f, pz = 0.f, pw = 0.f;
    for (; e + 8 <= eend; e += 8) {
        int s0 = es[e], s1 = es[e + 1], s2 = es[e + 2], s3 = es[e + 3];
        int s4 = es[e + 4], s5 = es[e + 5], s6 = es[e + 6], s7 = es[e + 7];
        float p0 = ep[e], p1 = ep[e + 1], p2 = ep[e + 2], p3 = ep[e + 3];
        float p4 = ep[e + 4], p5 = ep[e + 5], p6 = ep[e + 6], p7 = ep[e + 7];
        float4 v0 = *reinterpret_cast<const float4*>(&x[(size_t)s0 * 64 + c4]);
        float4 v1 = *reinterpret_cast<const float4*>(&x[(size_t)s1 * 64 + c4]);
        float4 v2 = *reinterpret_cast<const float4*>(&x[(size_t)s2 * 64 + c4]);
        float4 v3 = *reinterpret_cast<const float4*>(&x[(size_t)s3 * 64 + c4]);
        float4 v4 = *reinterpret_cast<const float4*>(&x[(size_t)s4 * 64 + c4]);
        float4 v5 = *reinterpret_cast<const float4*>(&x[(size_t)s5 * 64 + c4]);
        float4 v6 = *reinterpret_cast<const float4*>(&x[(size_t)s6 * 64 + c4]);
        float4 v7 = *reinterpret_cast<const float4*>(&x[(size_t)s7 * 64 + c4]);
        // math: two 4-edge groups, exactly the original sequence
        sx += (v0.x + v1.x) + (v2.x + v3.x);
        sy += (v0.y + v1.y) + (v2.y + v3.y);
        sz += (v0.z + v1.z) + (v2.z + v3.z);
        sw += (v0.w + v1.w) + (v2.w + v3.w);
        px = fmaf(p0, v0.x, fmaf(p1, v1.x, fmaf(p2, v2.x, fmaf(p3, v3.x, px))));
        py = fmaf(p0, v0.y, fmaf(p1, v1.y, fmaf(p2, v2.y, fmaf(p3, v3.y, py))));
        pz = fmaf(p0, v0.z, fmaf(p1, v1.z, fmaf(p2, v2.z, fmaf(p3, v3.z, pz))));
        pw = fmaf(p0, v0.w, fmaf(p1, v1.w, fmaf(p2, v2.w, fmaf(p3, v3.w, pw))));
        sx += (v4.x + v5.x) + (v6.x + v7.x);
        sy += (v4.y + v5.y) + (v6.y + v7.y);
        sz += (v4.z + v5.z) + (v6.z + v7.z);
        sw += (v4.w + v5.w) + (v6.w + v7.w);
        px = fmaf(p4, v4.x, fmaf(p5, v5.x, fmaf(p6, v6.x, fmaf(p7, v7.x, px))));
        py = fmaf(p4, v4.y, fmaf(p5, v5.y, fmaf(p6, v6.y, fmaf(p7, v7.y, py))));
        pz = fmaf(p4, v4.z, fmaf(p5, v5.z, fmaf(p6, v6.z, fmaf(p7, v7.z, pz))));
        pw = fmaf(p4, v4.w, fmaf(p5, v5.w, fmaf(p6, v6.w, fmaf(p7, v7.w, pw))));
    }
    for (; e + 4 <= eend; e += 4) {
        int s0 = es[e], s1 = es[e + 1], s2 = es[e + 2], s3 = es[e + 3];
        float p0 = ep[e], p1 = ep[e + 1], p2 = ep[e + 2], p3 = ep[e + 3];
        float4 v0 = *reinterpret_cast<const float4*>(&x[(size_t)s0 * 64 + c4]);
        float4 v1 = *reinterpret_cast<const float4*>(&x[(size_t)s1 * 64 + c4]);
        float4 v2 = *reinterpret_cast<const float4*>(&x[(size_t)s2 * 64 + c4]);
        float4 v3 = *reinterpret_cast<const float4*>(&x[(size_t)s3 * 64 + c4]);
        sx += (v0.x + v1.x) + (v2.x + v3.x);
        sy += (v0.y + v1.y) + (v2.y + v3.y);
        sz += (v0.z + v1.z) + (v2.z + v3.z);
        sw += (v0.w + v1.w) + (v2.w + v3.w);
        px = fmaf(p0, v0.x, fmaf(p1, v1.x, fmaf(p2, v2.x, fmaf(p3, v3.x, px))));
        py = fmaf(p0, v0.y, fmaf(p1, v1.y, fmaf(p2, v2.y, fmaf(p3, v3.y, py))));
        pz = fmaf(p0, v0.z, fmaf(p1, v1.z, fmaf(p2, v2.z, fmaf(p3, v3.z, pz))));
        pw = fmaf(p0, v0.w, fmaf(p1, v1.w, fmaf(p2, v2.w, fmaf(p3, v3.w, pw))));
    }
    for (; e < eend; ++e) {
        int s = es[e];
        float pe = ep[e];
        float4 v = *reinterpret_cast<const float4*>(&x[(size_t)s * 64 + c4]);
        sx += v.x; sy += v.y; sz += v.z; sw += v.w;
        px = fmaf(pe, v.x, px); py = fmaf(pe, v.y, py);
        pz = fmaf(pe, v.z, pz); pw = fmaf(pe, v.w, pw);
    }
    float w = invd[node];
    float4 a0 = make_float4((sx - px) * w, (sy - py) * w, (sz - pz) * w, (sw - pw) * w);
    float4 a1 = make_float4(px * w, py * w, pz * w, pw * w);
    *reinterpret_cast<float4*>(&agg[(size_t)node * 128 + c4]) = a0;
    *reinterpret_cast<float4*>(&agg[(size_t)node * 128 + 64 + c4]) = a1;
}

// ---------------------------------------------------------------------------
// Hidden GEMM, double-buffered 64-row tiles (r5/r8 best variant, unchanged).
// r9 (global-B) and r10 (scalar-B) both regressed: LDS-B is the plateau.
// ---------------------------------------------------------------------------
__global__ __launch_bounds__(256) void hidden_gemm_db(
    const float* __restrict__ agg, const float* __restrict__ in,
    const float* __restrict__ B, const float* __restrict__ bias,
    int n, int mode, float* __restrict__ u_out,
    const float* __restrict__ hbuf, const float* __restrict__ acc_in,
    float* __restrict__ acc_out, float* __restrict__ t_out,
    float c1, float c2, float c3) {
    __shared__ __align__(16) float As[2][16][68];
    __shared__ __align__(16) float Bs[2][16][68];
    const int t = threadIdx.x;
    const int row0 = blockIdx.x * 64;
    const int ty = t >> 4, tx = t & 15;
    const int lrow = t >> 2, lk = (t & 3) << 2;
    const int bkk = t >> 4, bcol = (t & 15) << 2;

    float4 av = make_float4(0.f, 0.f, 0.f, 0.f);
    {
        int r = row0 + lrow;
        if (r < n) av = *reinterpret_cast<const float4*>(&agg[(size_t)r * 128 + lk]);
    }
    float4 bv = *reinterpret_cast<const float4*>(&B[(size_t)bkk * 64 + bcol]);
    As[0][lk + 0][lrow] = av.x; As[0][lk + 1][lrow] = av.y;
    As[0][lk + 2][lrow] = av.z; As[0][lk + 3][lrow] = av.w;
    *reinterpret_cast<float4*>(&Bs[0][bkk][bcol]) = bv;
    __syncthreads();

    float acc[4][4];
    #pragma unroll
    for (int i = 0; i < 4; ++i)
        #pragma unroll
        for (int j = 0; j < 4; ++j) acc[i][j] = 0.f;

    for (int kt = 0; kt < 12; ++kt) {
        const int cur = kt & 1;
        if (kt + 1 < 12) {
            int k0 = (kt + 1) << 4;
            int r = row0 + lrow;
            int kk = k0 + lk;
            av = make_float4(0.f, 0.f, 0.f, 0.f);
            if (r < n)
                av = (kk < 128)
                    ? *reinterpret_cast<const float4*>(&agg[(size_t)r * 128 + kk])
                    : *reinterpret_cast<const float4*>(&in[(size_t)r * 64 + (kk - 128)]);
            bv = *reinterpret_cast<const float4*>(&B[(size_t)(k0 + bkk) * 64 + bcol]);
        }
        #pragma unroll
        for (int kk = 0; kk < 16; ++kk) {
            float4 a4 = *reinterpret_cast<const float4*>(&As[cur][kk][ty << 2]);
            float4 b4 = *reinterpret_cast<const float4*>(&Bs[cur][kk][tx << 2]);
            float aa[4] = {a4.x, a4.y, a4.z, a4.w};
            float bb[4] = {b4.x, b4.y, b4.z, b4.w};
            #pragma unroll
            for (int i = 0; i < 4; ++i)
                #pragma unroll
                for (int j = 0; j < 4; ++j)
                    acc[i][j] = fmaf(aa[i], bb[j], acc[i][j]);
        }
        if (kt + 1 < 12) {
            const int nx = cur ^ 1;
            As[nx][lk + 0][lrow] = av.x; As[nx][lk + 1][lrow] = av.y;
            As[nx][lk + 2][lrow] = av.z; As[nx][lk + 3][lrow] = av.w;
            *reinterpret_cast<float4*>(&Bs[nx][bkk][bcol]) = bv;
        }
        __syncthreads();
    }

    float4 bia = *reinterpret_cast<const float4*>(&bias[tx << 2]);
    #pragma unroll
    for (int i = 0; i < 4; ++i) {
        int r = row0 + (ty << 2) + i;
        if (r >= n) continue;
        size_t idx = (size_t)r * 64 + (tx << 2);
        float4 v = make_float4(acc[i][0] + bia.x, acc[i][1] + bia.y,
                               acc[i][2] + bia.z, acc[i][3] + bia.w);
        if (mode == 0) {
            *reinterpret_cast<float4*>(&u_out[idx]) = v;
        } else {
            float4 ai = make_float4(0.f, 0.f, 0.f, 0.f);
            if (acc_in) ai = *reinterpret_cast<const float4*>(&acc_in[idx]);
            float4 an = make_float4(ai.x + c3 * v.x, ai.y + c3 * v.y,
                                    ai.z + c3 * v.z, ai.w + c3 * v.w);
            *reinterpret_cast<float4*>(&acc_out[idx]) = an;
            float4 hb = *reinterpret_cast<const float4*>(&hbuf[idx]);
            float4 to = make_float4(hb.x + c1 * v.x + c2 * an.x,
                                    hb.y + c1 * v.y + c2 * an.y,
                                    hb.z + c1 * v.z + c2 * an.z,
                                    hb.w + c1 * v.w + c2 * an.w);
            *reinterpret_cast<float4*>(&t_out[idx]) = to;
        }
    }
}

// ---------------------------------------------------------------------------
// conv1 GEMM: r4's exact structure (best measured: 81 us). Single-buffer,
// 256 threads, micro 4x12, A+B in LDS.
// ---------------------------------------------------------------------------
__global__ __launch_bounds__(256) void conv1_gemm(const float* __restrict__ x,
                                                  const float* __restrict__ B,
                                                  int n, float* __restrict__ yz,
                                                  float* __restrict__ base,
                                                  const float* __restrict__ b1) {
    __shared__ __align__(16) float As[16][68];
    __shared__ __align__(16) float Bs[16][200];
    const int t = threadIdx.x;
    const int row0 = blockIdx.x * 64;
    const int ty = t >> 4, tx = t & 15;
    const int lrow = t >> 2, lk = (t & 3) << 2;
    const int bkk = t >> 4, bcol = (t & 15) << 2;
    float acc[4][12];
    #pragma unroll
    for (int i = 0; i < 4; ++i)
        #pragma unroll
        for (int j = 0; j < 12; ++j) acc[i][j] = 0.f;

    for (int kt = 0; kt < 16; ++kt) {
        int k0 = kt << 4;
        float4 av = make_float4(0.f, 0.f, 0.f, 0.f);
        int r = row0 + lrow;
        if (r < n) av = *reinterpret_cast<const float4*>(&x[(size_t)r * 256 + k0 + lk]);
        As[lk + 0][lrow] = av.x; As[lk + 1][lrow] = av.y;
        As[lk + 2][lrow] = av.z; As[lk + 3][lrow] = av.w;
        const float* bp = &B[(size_t)(k0 + bkk) * 192 + bcol];
        *reinterpret_cast<float4*>(&Bs[bkk][bcol])       = *reinterpret_cast<const float4*>(bp);
        *reinterpret_cast<float4*>(&Bs[bkk][bcol + 64])  = *reinterpret_cast<const float4*>(bp + 64);
        *reinterpret_cast<float4*>(&Bs[bkk][bcol + 128]) = *reinterpret_cast<const float4*>(bp + 128);
        __syncthreads();
        #pragma unroll
        for (int kk = 0; kk < 16; ++kk) {
            float4 a4 = *reinterpret_cast<const float4*>(&As[kk][ty << 2]);
            float4 b0 = *reinterpret_cast<const float4*>(&Bs[kk][tx << 2]);
            float4 b1v = *reinterpret_cast<const float4*>(&Bs[kk][(tx << 2) + 64]);
            float4 b2v = *reinterpret_cast<const float4*>(&Bs[kk][(tx << 2) + 128]);
            float aa[4] = {a4.x, a4.y, a4.z, a4.w};
            float bb[12] = {b0.x, b0.y, b0.z, b0.w, b1v.x, b1v.y, b1v.z, b1v.w,
                            b2v.x, b2v.y, b2v.z, b2v.w};
            #pragma unroll
            for (int i = 0; i < 4; ++i)
                #pragma unroll
                for (int j = 0; j < 12; ++j)
                    acc[i][j] = fmaf(aa[i], bb[j], acc[i][j]);
        }
        __syncthreads();
    }

    float4 bb4 = *reinterpret_cast<const float4*>(&b1[tx << 2]);
    #pragma unroll
    for (int i = 0; i < 4; ++i) {
        int r = row0 + (ty << 2) + i;
        if (r >= n) continue;
        float4 q0 = make_float4(acc[i][0], acc[i][1], acc[i][2], acc[i][3]);
        float4 q1 = make_float4(acc[i][4], acc[i][5], acc[i][6], acc[i][7]);
        float4 q2 = make_float4(acc[i][8] + bb4.x, acc[i][9] + bb4.y,
                                acc[i][10] + bb4.z, acc[i][11] + bb4.w);
        *reinterpret_cast<float4*>(&yz[(size_t)r * 128 + (tx << 2)]) = q0;
        *reinterpret_cast<float4*>(&yz[(size_t)r * 128 + 64 + (tx << 2)]) = q1;
        *reinterpret_cast<float4*>(&base[(size_t)r * 64 + (tx << 2)]) = q2;
    }
}

// ---------------------------------------------------------------------------
// conv1 edge transform: 8 lanes/node x 8 ch, 4-edge LOAD batch (16 loads
// outstanding), 2-edge math grouping preserved -> bitwise identical.
// ---------------------------------------------------------------------------
__global__ __launch_bounds__(256) void edge_tf64_u4(const float* __restrict__ yz,
                                                    const int* __restrict__ rowp,
                                                    const int* __restrict__ es,
                                                    const float* __restrict__ ep,
                                                    const float* __restrict__ invd,
                                                    const float* __restrict__ base,
                                                    float* __restrict__ out, int n) {
    int gid = blockIdx.x * 256 + threadIdx.x;
    int node = gid >> 3;
    if (node >= n) return;
    int c8 = (gid & 7) << 3;
    int e = rowp[node], eend = rowp[node + 1];
    float a[8] = {0.f, 0.f, 0.f, 0.f, 0.f, 0.f, 0.f, 0.f};
    for (; e + 4 <= eend; e += 4) {
        int s0 = es[e], s1 = es[e + 1], s2 = es[e + 2], s3 = es[e + 3];
        float p0 = ep[e], p1 = ep[e + 1], p2 = ep[e + 2], p3 = ep[e + 3];
        float4 y0a = *reinterpret_cast<const float4*>(&yz[(size_t)s0 * 128 + c8]);
        float4 y0b = *reinterpret_cast<const float4*>(&yz[(size_t)s0 * 128 + c8 + 4]);
        float4 z0a = *reinterpret_cast<const float4*>(&yz[(size_t)s0 * 128 + 64 + c8]);
        float4 z0b = *reinterpret_cast<const float4*>(&yz[(size_t)s0 * 128 + 64 + c8 + 4]);
        float4 y1a = *reinterpret_cast<const float4*>(&yz[(size_t)s1 * 128 + c8]);
        float4 y1b = *reinterpret_cast<const float4*>(&yz[(size_t)s1 * 128 + c8 + 4]);
        float4 z1a = *reinterpret_cast<const float4*>(&yz[(size_t)s1 * 128 + 64 + c8]);
        float4 z1b = *reinterpret_cast<const float4*>(&yz[(size_t)s1 * 128 + 64 + c8 + 4]);
        float4 y2a = *reinterpret_cast<const float4*>(&yz[(size_t)s2 * 128 + c8]);
        float4 y2b = *reinterpret_cast<const float4*>(&yz[(size_t)s2 * 128 + c8 + 4]);
        float4 z2a = *reinterpret_cast<const float4*>(&yz[(size_t)s2 * 128 + 64 + c8]);
        float4 z2b = *reinterpret_cast<const float4*>(&yz[(size_t)s2 * 128 + 64 + c8 + 4]);
        float4 y3a = *reinterpret_cast<const float4*>(&yz[(size_t)s3 * 128 + c8]);
        float4 y3b = *reinterpret_cast<const float4*>(&yz[(size_t)s3 * 128 + c8 + 4]);
        float4 z3a = *reinterpret_cast<const float4*>(&yz[(size_t)s3 * 128 + 64 + c8]);
        float4 z3b = *reinterpret_cast<const float4*>(&yz[(size_t)s3 * 128 + 64 + c8 + 4]);
        const float* fy0 = &y0a.x; const float* gy0 = &y0b.x;
        const float* fz0 = &z0a.x; const float* gz0 = &z0b.x;
        const float* fy1 = &y1a.x; const float* gy1 = &y1b.x;
        const float* fz1 = &z1a.x; const float* gz1 = &z1b.x;
        const float* fy2 = &y2a.x; const float* gy2 = &y2b.x;
        const float* fz2 = &z2a.x; const float* gz2 = &z2b.x;
        const float* fy3 = &y3a.x; const float* gy3 = &y3b.x;
        const float* fz3 = &z3a.x; const float* gz3 = &z3b.x;
        // math: two 2-edge pairs, original sequence preserved
        #pragma unroll
        for (int j = 0; j < 4; ++j) {
            a[j]     += fmaf(p0, fz0[j] - fy0[j], fy0[j]) + fmaf(p1, fz1[j] - fy1[j], fy1[j]);
            a[4 + j] += fmaf(p0, gz0[j] - gy0[j], gy0[j]) + fmaf(p1, gz1[j] - gy1[j], gy1[j]);
        }
        #pragma unroll
        for (int j = 0; j < 4; ++j) {
            a[j]     += fmaf(p2, fz2[j] - fy2[j], fy2[j]) + fmaf(p3, fz3[j] - fy3[j], fy3[j]);
            a[4 + j] += fmaf(p2, gz2[j] - gy2[j], gy2[j]) + fmaf(p3, gz3[j] - gy3[j], gy3[j]);
        }
    }
    for (; e + 2 <= eend; e += 2) {
        int s0 = es[e], s1 = es[e + 1];
        float p0 = ep[e], p1 = ep[e + 1];
        float4 y0a = *reinterpret_cast<const float4*>(&yz[(size_t)s0 * 128 + c8]);
        float4 y0b = *reinterpret_cast<const float4*>(&yz[(size_t)s0 * 128 + c8 + 4]);
        float4 z0a = *reinterpret_cast<const float4*>(&yz[(size_t)s0 * 128 + 64 + c8]);
        float4 z0b = *reinterpret_cast<const float4*>(&yz[(size_t)s0 * 128 + 64 + c8 + 4]);
        float4 y1a = *reinterpret_cast<const float4*>(&yz[(size_t)s1 * 128 + c8]);
        float4 y1b = *reinterpret_cast<const float4*>(&yz[(size_t)s1 * 128 + c8 + 4]);
        float4 z1a = *reinterpret_cast<const float4*>(&yz[(size_t)s1 * 128 + 64 + c8]);
        float4 z1b = *reinterpret_cast<const float4*>(&yz[(size_t)s1 * 128 + 64 + c8 + 4]);
        const float* ya0 = &y0a.x; const float* yb0 = &y0b.x;
        const float* za0 = &z0a.x; const float* zb0 = &z0b.x;
        const float* ya1 = &y1a.x; const float* yb1 = &y1b.x;
        const float* za1 = &z1a.x; const float* zb1 = &z1b.x;
        #pragma unroll
        for (int j = 0; j < 4; ++j) {
            a[j]     += fmaf(p0, za0[j] - ya0[j], ya0[j]) + fmaf(p1, za1[j] - ya1[j], ya1[j]);
            a[4 + j] += fmaf(p0, zb0[j] - yb0[j], yb0[j]) + fmaf(p1, zb1[j] - yb1[j], yb1[j]);
        }
    }
    for (; e < eend; ++e) {
        int s = es[e];
        float pe = ep[e];
        float4 ya = *reinterpret_cast<const float4*>(&yz[(size_t)s * 128 + c8]);
        float4 yb = *reinterpret_cast<const float4*>(&yz[(size_t)s * 128 + c8 + 4]);
        float4 za = *reinterpret_cast<const float4*>(&yz[(size_t)s * 128 + 64 + c8]);
        float4 zb = *reinterpret_cast<const float4*>(&yz[(size_t)s * 128 + 64 + c8 + 4]);
        const float* fy = &ya.x; const float* gy = &yb.x;
        const float* fz = &za.x; const float* gz = &zb.x;
        #pragma unroll
        for (int j = 0; j < 4; ++j) {
            a[j]     += fmaf(pe, fz[j] - fy[j], fy[j]);
            a[4 + j] += fmaf(pe, gz[j] - gy[j], gy[j]);
        }
    }
    float w = invd[node];
    size_t idx = (size_t)node * 64 + c8;
    float4 ba = *reinterpret_cast<const float4*>(&base[idx]);
    float4 bbv = *reinterpret_cast<const float4*>(&base[idx + 4]);
    float4 o0 = make_float4(tanhf(fmaf(a[0], w, ba.x)), tanhf(fmaf(a[1], w, ba.y)),
                            tanhf(fmaf(a[2], w, ba.z)), tanhf(fmaf(a[3], w, ba.w)));
    float4 o1 = make_float4(tanhf(fmaf(a[4], w, bbv.x)), tanhf(fmaf(a[5], w, bbv.y)),
                            tanhf(fmaf(a[6], w, bbv.z)), tanhf(fmaf(a[7], w, bbv.w)));
    *reinterpret_cast<float4*>(&out[idx]) = o0;
    *reinterpret_cast<float4*>(&out[idx + 4]) = o1;
}

// ---------------------------------------------------------------------------
// conv2 edge transform + log_softmax: 8-edge load batch, 4-edge math grouping
// preserved.
// ---------------------------------------------------------------------------
__global__ __launch_bounds__(256) void edge_tf16_lsm(const float* __restrict__ yz,
                                                     const int* __restrict__ rowp,
                                                     const int* __restrict__ es,
                                                     const float* __restrict__ ep,
                                                     const float* __restrict__ invd,
                                                     const float* __restrict__ base,
                                                     float* __restrict__ out, int n) {
    int gid = blockIdx.x * 256 + threadIdx.x;
    int node = gid >> 4;
    if (node >= n) return;
    int c = gid & 15;
    int e = rowp[node], eend = rowp[node + 1];
    float a = 0.f;
    for (; e + 8 <= eend; e += 8) {
        int s0 = es[e], s1 = es[e + 1], s2 = es[e + 2], s3 = es[e + 3];
        int s4 = es[e + 4], s5 = es[e + 5], s6 = es[e + 6], s7 = es[e + 7];
        float p0 = ep[e], p1 = ep[e + 1], p2 = ep[e + 2], p3 = ep[e + 3];
        float p4 = ep[e + 4], p5 = ep[e + 5], p6 = ep[e + 6], p7 = ep[e + 7];
        float y0 = yz[(size_t)s0 * 32 + c], z0 = yz[(size_t)s0 * 32 + 16 + c];
        float y1 = yz[(size_t)s1 * 32 + c], z1 = yz[(size_t)s1 * 32 + 16 + c];
        float y2 = yz[(size_t)s2 * 32 + c], z2 = yz[(size_t)s2 * 32 + 16 + c];
        float y3 = yz[(size_t)s3 * 32 + c], z3 = yz[(size_t)s3 * 32 + 16 + c];
        float y4 = yz[(size_t)s4 * 32 + c], z4 = yz[(size_t)s4 * 32 + 16 + c];
        float y5 = yz[(size_t)s5 * 32 + c], z5 = yz[(size_t)s5 * 32 + 16 + c];
        float y6 = yz[(size_t)s6 * 32 + c], z6 = yz[(size_t)s6 * 32 + 16 + c];
        float y7 = yz[(size_t)s7 * 32 + c], z7 = yz[(size_t)s7 * 32 + 16 + c];
        a += fmaf(p0, z0 - y0, y0);
        a += fmaf(p1, z1 - y1, y1);
        a += fmaf(p2, z2 - y2, y2);
        a += fmaf(p3, z3 - y3, y3);
        a += fmaf(p4, z4 - y4, y4);
        a += fmaf(p5, z5 - y5, y5);
        a += fmaf(p6, z6 - y6, y6);
        a += fmaf(p7, z7 - y7, y7);
    }
    for (; e + 4 <= eend; e += 4) {
        int s0 = es[e], s1 = es[e + 1], s2 = es[e + 2], s3 = es[e + 3];
        float p0 = ep[e], p1 = ep[e + 1], p2 = ep[e + 2], p3 = ep[e + 3];
        float y0 = yz[(size_t)s0 * 32 + c], z0 = yz[(size_t)s0 * 32 + 16 + c];
        float y1 = yz[(size_t)s1 * 32 + c], z1 = yz[(size_t)s1 * 32 + 16 + c];
        float y2 = yz[(size_t)s2 * 32 + c], z2 = yz[(size_t)s2 * 32 + 16 + c];
        float y3 = yz[(size_t)s3 * 32 + c], z3 = yz[(size_t)s3 * 32 + 16 + c];
        a += fmaf(p0, z0 - y0, y0);
        a += fmaf(p1, z1 - y1, y1);
        a += fmaf(p2, z2 - y2, y2);
        a += fmaf(p3, z3 - y3, y3);
    }
    for (; e < eend; ++e) {
        int s = es[e]; float pe = ep[e];
        float y = yz[(size_t)s * 32 + c], z = yz[(size_t)s * 32 + 16 + c];
        a += fmaf(pe, z - y, y);
    }
    float o = tanhf(a * invd[node] + base[(size_t)node * 16 + c]);
    float m = o;
    #pragma unroll
    for (int off = 8; off >= 1; off >>= 1) m = fmaxf(m, __shfl_xor(m, off, 16));
    float ex = expf(o - m);
    float s = ex;
    #pragma unroll
    for (int off = 8; off >= 1; off >>= 1) s += __shfl_xor(s, off, 16);
    out[(size_t)node * 16 + c] = (o - m) - logf(s);
}

// ---------------------------------------------------------------------------
// conv2 GEMM (K=64, M=48), r8's LDS-A + LDS-B structure via generic tile
// ---------------------------------------------------------------------------
__global__ __launch_bounds__(256) void gemm_tiled(
    const float* __restrict__ A0, int lda0, int K0,
    const float* __restrict__ A1, int lda1,
    const float* __restrict__ B,
    int n, int K, int M,
    float* __restrict__ out0, int w0, const float* __restrict__ bias0,
    float* __restrict__ out1, int w1, const float* __restrict__ bias1,
    int split) {
    __shared__ __align__(16) float As[16][68];
    __shared__ __align__(16) float Bs[16][68];
    const int t = threadIdx.x;
    const int row0 = blockIdx.x * 64;
    const int col0 = blockIdx.y * 64;
    const int ty = t >> 4, tx = t & 15;
    const int lrow = t >> 2, lk = (t & 3) << 2;
    const int bkk = t >> 4, bcol = (t & 15) << 2;
    float acc[4][4];
    #pragma unroll
    for (int i = 0; i < 4; ++i)
        #pragma unroll
        for (int j = 0; j < 4; ++j) acc[i][j] = 0.f;

    for (int k0 = 0; k0 < K; k0 += 16) {
        float4 av = make_float4(0.f, 0.f, 0.f, 0.f);
        {
            int r = row0 + lrow;
            if (r < n) {
                int kk = k0 + lk;
                const float* src = (kk < K0)
                    ? (A0 + (size_t)r * lda0 + kk)
                    : (A1 + (size_t)r * lda1 + (kk - K0));
                av = *reinterpret_cast<const float4*>(src);
            }
        }
        float4 bv = make_float4(0.f, 0.f, 0.f, 0.f);
        {
            int c = col0 + bcol;
            int kk = k0 + bkk;
            if (c < M) bv = *reinterpret_cast<const float4*>(B + (size_t)kk * M + c);
        }
        As[lk + 0][lrow] = av.x; As[lk + 1][lrow] = av.y;
        As[lk + 2][lrow] = av.z; As[lk + 3][lrow] = av.w;
        *reinterpret_cast<float4*>(&Bs[bkk][bcol]) = bv;
        __syncthreads();
        #pragma unroll
        for (int kk = 0; kk < 16; ++kk) {
            float4 a4 = *reinterpret_cast<const float4*>(&As[kk][ty << 2]);
            float4 b4 = *reinterpret_cast<const float4*>(&Bs[kk][tx << 2]);
            float aa[4] = {a4.x, a4.y, a4.z, a4.w};
            float bb[4] = {b4.x, b4.y, b4.z, b4.w};
            #pragma unroll
            for (int i = 0; i < 4; ++i)
                #pragma unroll
                for (int j = 0; j < 4; ++j)
                    acc[i][j] = fmaf(aa[i], bb[j], acc[i][j]);
        }
        __syncthreads();
    }

    #pragma unroll
    for (int i = 0; i < 4; ++i) {
        int r = row0 + (ty << 2) + i;
        if (r >= n) continue;
        #pragma unroll
        for (int j = 0; j < 4; ++j) {
            int c = col0 + (tx << 2) + j;
            if (c >= M) continue;
            float v = acc[i][j];
            if (c < split) {
                if (bias0) v += bias0[c];
                out0[(size_t)r * w0 + c] = v;
            } else {
                int cc = c - split;
                if (bias1) v += bias1[cc];
                out1[(size_t)r * w1 + cc] = v;
            }
        }
    }
}

// ---------------------------------------------------------------------------
// Host-side launcher
// ---------------------------------------------------------------------------

static void hidden_conv(hipStream_t stream, const float* in, float* agg,
                        const int* rowp, const int* es, const float* ep,
                        const float* invd, const float* Bc, const float* bias, int n,
                        int mode, float* u_out,
                        const float* h, const float* acc_in, float* acc_out,
                        float* t_out, float c1, float c2, float c3) {
    edge_agg64_u8<<<ceil_div(n * 16, 256), 256, 0, stream>>>(in, rowp, es, ep, invd,
                                                             agg, n);
    hidden_gemm_db<<<ceil_div(n, 64), 256, 0, stream>>>(agg, in, Bc, bias, n, mode,
                                                        u_out, h, acc_in, acc_out,
                                                        t_out, c1, c2, c3);
}

extern "C" void kernel_launch(void* const* d_in, const int* in_sizes, int n_in,
                              void* d_out, int out_size, void* d_ws, size_t ws_size,
                              hipStream_t stream) {
    const float* x  = (const float*)d_in[0];
    const float* pE = (const float*)d_in[1];
    const int*   sr = (const int*)d_in[2];
    const int*   ds = (const int*)d_in[3];
    const float* W1 = (const float*)d_in[4];
    const float* R1 = (const float*)d_in[5];
    const float* b1 = (const float*)d_in[6];
    const float* Wa = (const float*)d_in[7];
    const float* Ra = (const float*)d_in[8];
    const float* ba = (const float*)d_in[9];
    const float* Wb = (const float*)d_in[10];
    const float* Rb = (const float*)d_in[11];
    const float* bb = (const float*)d_in[12];
    const float* W2 = (const float*)d_in[13];
    const float* R2 = (const float*)d_in[14];
    const float* b2 = (const float*)d_in[15];
    const int n = in_sizes[0] / 256;
    const int E = in_sizes[2];
    float* out = (float*)d_out;

    char* w = (char*)d_ws;
    auto alloc = [&](size_t bytes) -> void* {
        void* ptr = (void*)w;
        w += (bytes + 255) & ~(size_t)255;
        return ptr;
    };
    int nscan = ceil_div(n, 2048);
    int*   deg  = (int*)alloc((size_t)n * 4);
    int*   fill = (int*)alloc((size_t)n * 4);
    int*   rowp = (int*)alloc((size_t)(n + 1) * 4);
    float* invd = (float*)alloc((size_t)n * 4);
    int*   bsum = (int*)alloc((size_t)256 * 4);
    int*   ei   = (int*)alloc((size_t)E * 4);
    int*   es   = (int*)alloc((size_t)E * 4);
    float* ep   = (float*)alloc((size_t)E * 4);
    float* Bc1  = (float*)alloc((size_t)256 * 192 * 4);
    float* Bca  = (float*)alloc((size_t)192 * 64 * 4);
    float* Bcb  = (float*)alloc((size_t)192 * 64 * 4);
    float* Bc2  = (float*)alloc((size_t)64 * 48 * 4);
    float* big0 = (float*)alloc((size_t)n * 128 * 4);  // yz / agg buffer
    float* big1 = (float*)alloc((size_t)n * 64 * 4);   // base buffer
    float* h    = (float*)alloc((size_t)n * 64 * 4);
    float* u    = (float*)alloc((size_t)n * 64 * 4);
    float* tb   = (float*)alloc((size_t)n * 64 * 4);
    float* acc  = (float*)alloc((size_t)n * 64 * 4);

    setup_zero_pack<<<288, 256, 0, stream>>>(deg, fill, n, W1, R1, Wa, Ra, Wb, Rb,
                                             W2, R2, Bc1, Bca, Bcb, Bc2);
    hist_kernel<<<ceil_div(E, 256), 256, 0, stream>>>(ds, deg, E);
    scan_blocksum<<<nscan, 256, 0, stream>>>(deg, bsum, n);
    scan_tops<<<1, 256, 0, stream>>>(bsum, nscan);
    scan_final<<<nscan, 256, 0, stream>>>(deg, bsum, rowp, invd, n, E);
    scatter_idx<<<ceil_div(E, 256), 256, 0, stream>>>(ds, rowp, fill, ei, E);
    sort_fill<<<ceil_div(n, 256), 256, 0, stream>>>(rowp, ei, sr, pE, es, ep, n);

    // conv1: x @ [W1_0|W1_1|R1] -> yz(big0), base(big1)+b1; then edge transform
    conv1_gemm<<<ceil_div(n, 64), 256, 0, stream>>>(x, Bc1, n, big0, big1, b1);
    edge_tf64_u4<<<ceil_div(n * 8, 256), 256, 0, stream>>>(big0, rowp, es, ep, invd,
                                                           big1, h, n);

    // RK4 over f(y) = conv_b(conv_a(y)), T=3
    // k1
    hidden_conv(stream, h, big0, rowp, es, ep, invd, Bca, ba, n, 0, u,
                nullptr, nullptr, nullptr, nullptr, 0.f, 0.f, 0.f);
    hidden_conv(stream, u, big0, rowp, es, ep, invd, Bcb, bb, n, 1, nullptr,
                h, nullptr, acc, tb, 1.5f, 0.f, 1.f);
    // k2
    hidden_conv(stream, tb, big0, rowp, es, ep, invd, Bca, ba, n, 0, u,
                nullptr, nullptr, nullptr, nullptr, 0.f, 0.f, 0.f);
    hidden_conv(stream, u, big0, rowp, es, ep, invd, Bcb, bb, n, 1, nullptr,
                h, acc, acc, tb, 1.5f, 0.f, 2.f);
    // k3
    hidden_conv(stream, tb, big0, rowp, es, ep, invd, Bca, ba, n, 0, u,
                nullptr, nullptr, nullptr, nullptr, 0.f, 0.f, 0.f);
    hidden_conv(stream, u, big0, rowp, es, ep, invd, Bcb, bb, n, 1, nullptr,
                h, acc, acc, tb, 3.f, 0.f, 2.f);
    // k4: t_out becomes h_new = h + 0.5*(k1+2k2+2k3+k4)
    hidden_conv(stream, tb, big0, rowp, es, ep, invd, Bca, ba, n, 0, u,
                nullptr, nullptr, nullptr, nullptr, 0.f, 0.f, 0.f);
    hidden_conv(stream, u, big0, rowp, es, ep, invd, Bcb, bb, n, 1, nullptr,
                h, acc, acc, tb, 0.f, 0.5f, 1.f);

    // conv2: h_new @ [W2_0|W2_1|R2] -> yz2(big0,w=32), base2(big1,w=16)+b2
    gemm_tiled<<<dim3(ceil_div(n, 64), 1), 256, 0, stream>>>(
        tb, 64, 64, nullptr, 0, Bc2, n, 64, 48,
        big0, 32, nullptr, big1, 16, b2, 32);
    edge_tf16_lsm<<<ceil_div(n * 16, 256), 256, 0, stream>>>(big0, rowp, es, ep, invd,
                                                             big1, out, n);
}